// Round 1
// baseline (1179.284 us; speedup 1.0000x reference)
//
#include <hip/hip_runtime.h>
#include <hip/hip_bf16.h>

// QuantizedLinear: y[M,N] = x[M,K] . W[N,K]^T + bias ; W = int4 * groupscale(G=128)
// Round 0: two-pass (dequant to bf16 in ws, then m97-structure 128x128 MFMA GEMM).

typedef __bf16 bf16_t;
typedef __bf16 bf16x8 __attribute__((ext_vector_type(8)));
typedef float f32x4 __attribute__((ext_vector_type(4)));
typedef __attribute__((address_space(3))) unsigned char lds_byte;
typedef __attribute__((address_space(1))) unsigned char gmem_byte;

#define BM 128
#define BN 128
#define BK 32

// ---------------- pre-pass 1: x fp32 -> bf16 ----------------
__global__ void cvt_x_kernel(const float* __restrict__ x, bf16_t* __restrict__ xb, long n8) {
  const long stride = (long)gridDim.x * blockDim.x;
  for (long i = (long)blockIdx.x * blockDim.x + threadIdx.x; i < n8; i += stride) {
    const float4* p = reinterpret_cast<const float4*>(x + i * 8);
    const float4 f0 = p[0];
    const float4 f1 = p[1];
    bf16x8 o;
    o[0] = (bf16_t)f0.x; o[1] = (bf16_t)f0.y; o[2] = (bf16_t)f0.z; o[3] = (bf16_t)f0.w;
    o[4] = (bf16_t)f1.x; o[5] = (bf16_t)f1.y; o[6] = (bf16_t)f1.z; o[7] = (bf16_t)f1.w;
    *reinterpret_cast<bf16x8*>(xb + i * 8) = o;
  }
}

// ---------------- pre-pass 2: W int32(int4) * scale -> bf16 ----------------
__global__ void deq_w_kernel(const int* __restrict__ qw, const float* __restrict__ sc,
                             bf16_t* __restrict__ wb, int I, int G) {
  const int n = blockIdx.y;
  const int kb = blockIdx.x * blockDim.x + threadIdx.x;  // 8-wide chunk along K
  const int k = kb * 8;
  if (k >= I) return;
  const float s = sc[(size_t)n * (I / G) + k / G];  // G=128 so 8 consecutive k share a group
  const int4* qp = reinterpret_cast<const int4*>(qw + (size_t)n * I + k);
  const int4 q0 = qp[0];
  const int4 q1 = qp[1];
  bf16x8 o;
  o[0] = (bf16_t)((float)q0.x * s);
  o[1] = (bf16_t)((float)q0.y * s);
  o[2] = (bf16_t)((float)q0.z * s);
  o[3] = (bf16_t)((float)q0.w * s);
  o[4] = (bf16_t)((float)q1.x * s);
  o[5] = (bf16_t)((float)q1.y * s);
  o[6] = (bf16_t)((float)q1.z * s);
  o[7] = (bf16_t)((float)q1.w * s);
  *reinterpret_cast<bf16x8*>(wb + (size_t)n * I + k) = o;
}

// ---------------- GEMM: C[M,N] = A[M,K] . B[N,K]^T + bias ----------------
// 128x128 tile, BK=32, 4 waves (2x2), each wave 64x64 = 4x4 frags of 16x16x32 bf16 MFMA.
// Staging: global_load_lds width=16, double-buffered LDS, 1 barrier per K-step.
__launch_bounds__(256)
__global__ void gemm_bt_kernel(const bf16_t* __restrict__ A, const bf16_t* __restrict__ B,
                               const float* __restrict__ bias, float* __restrict__ C,
                               int M, int N, int K) {
  __shared__ __align__(16) bf16_t As[2][BM * BK];
  __shared__ __align__(16) bf16_t Bs[2][BM * BK];

  const int tid = threadIdx.x;
  const int lane = tid & 63;
  const int w = tid >> 6;            // wave 0..3
  const int wr = w >> 1;             // wave row (2)
  const int wc = w & 1;              // wave col (2)
  const int m0 = blockIdx.y * BM;
  const int n0 = blockIdx.x * BN;

  // staging decomposition: lane covers (row = l>>2, 16B chunk = l&3) of a 16-row slab
  const int srow = lane >> 2;
  const int schunk = lane & 3;

  f32x4 acc[4][4];
  const f32x4 zero = {0.f, 0.f, 0.f, 0.f};
#pragma unroll
  for (int i = 0; i < 4; ++i)
#pragma unroll
    for (int j = 0; j < 4; ++j) acc[i][j] = zero;

  const int nt = K / BK;

  auto stage = [&](int t, int buf) {
    const int k0 = t * BK;
#pragma unroll
    for (int j = 0; j < 2; ++j) {
      const int row = w * 32 + j * 16;  // wave-uniform base row of this 1KB slab
      const bf16_t* ga = A + (size_t)(m0 + row + srow) * K + k0 + schunk * 8;
      __builtin_amdgcn_global_load_lds((const gmem_byte*)ga,
                                       (lds_byte*)&As[buf][row * BK], 16, 0, 0);
      const bf16_t* gb = B + (size_t)(n0 + row + srow) * K + k0 + schunk * 8;
      __builtin_amdgcn_global_load_lds((const gmem_byte*)gb,
                                       (lds_byte*)&Bs[buf][row * BK], 16, 0, 0);
    }
  };

  auto compute = [&](int buf) {
    bf16x8 af[4], bfr[4];
    const int fr = lane & 15;
    const int kc = (lane >> 4) * 8;
#pragma unroll
    for (int i = 0; i < 4; ++i) {
      af[i]  = *reinterpret_cast<const bf16x8*>(&As[buf][(wr * 64 + i * 16 + fr) * BK + kc]);
      bfr[i] = *reinterpret_cast<const bf16x8*>(&Bs[buf][(wc * 64 + i * 16 + fr) * BK + kc]);
    }
#pragma unroll
    for (int i = 0; i < 4; ++i)
#pragma unroll
      for (int j = 0; j < 4; ++j)
        acc[i][j] = __builtin_amdgcn_mfma_f32_16x16x32_bf16(af[i], bfr[j], acc[i][j], 0, 0, 0);
  };

  stage(0, 0);
  __syncthreads();
  int cur = 0;
  for (int t = 0; t < nt - 1; ++t) {
    stage(t + 1, cur ^ 1);   // prefetch next tile while computing current
    compute(cur);
    __syncthreads();         // drains vmcnt + lgkm; next iter reads cur^1
    cur ^= 1;
  }
  compute(cur);

  // epilogue: C/D layout col = lane&15 (n), row = (lane>>4)*4 + r (m)  [m89-verified]
#pragma unroll
  for (int j = 0; j < 4; ++j) {
    const int n = n0 + wc * 64 + j * 16 + (lane & 15);
    const float bv = bias[n];
#pragma unroll
    for (int i = 0; i < 4; ++i) {
      const int mbase = m0 + wr * 64 + i * 16 + (lane >> 4) * 4;
#pragma unroll
      for (int r = 0; r < 4; ++r)
        C[(size_t)(mbase + r) * N + n] = acc[i][j][r] + bv;
    }
  }
}

extern "C" void kernel_launch(void* const* d_in, const int* in_sizes, int n_in,
                              void* d_out, int out_size, void* d_ws, size_t ws_size,
                              hipStream_t stream) {
  const float* x   = (const float*)d_in[0];
  const int* qw    = (const int*)d_in[1];
  const float* sc  = (const float*)d_in[2];
  const float* bias = (const float*)d_in[3];
  float* out = (float*)d_out;

  const long O = in_sizes[3];
  const long I = in_sizes[1] / O;          // 4096
  const long M = in_sizes[0] / I;          // 8192
  const long G = I / (in_sizes[2] / O);    // 128

  bf16_t* xb = (bf16_t*)d_ws;
  bf16_t* wb = xb + (size_t)M * I;
  const size_t need = ((size_t)M * I + (size_t)O * I) * sizeof(bf16_t);
  if (ws_size < need) return;  // clean failure signal: ws too small for two-pass plan

  cvt_x_kernel<<<2048, 256, 0, stream>>>(x, xb, M * I / 8);

  dim3 dgrid((unsigned)((I / 8 + 255) / 256), (unsigned)O);
  deq_w_kernel<<<dgrid, 256, 0, stream>>>(qw, sc, wb, (int)I, (int)G);

  dim3 ggrid((unsigned)(O / BN), (unsigned)(M / BM));
  gemm_bt_kernel<<<ggrid, 256, 0, stream>>>(xb, wb, bias, out, (int)M, (int)O, (int)I);
}

// Round 3
// 831.801 us; speedup vs baseline: 1.4177x; 1.4177x over previous
//
#include <hip/hip_runtime.h>
#include <hip/hip_bf16.h>

// QuantizedLinear: y[M,N] = x[M,K] . W[N,K]^T + bias ; W = int4 * groupscale(G=128)
// Round 2: 256x256 8-wave chunk-ring GEMM, race-fixed schedule (reads only u<=P+1),
//          + bank-conflict swizzle (swizzled read addr, pre-swizzled global source).

typedef __bf16 bf16_t;
typedef __bf16 bf16x8 __attribute__((ext_vector_type(8)));
typedef float f32x4 __attribute__((ext_vector_type(4)));
typedef __attribute__((address_space(3))) unsigned char lds_byte;
typedef __attribute__((address_space(1))) unsigned char gmem_byte;

// ---------------- pre-pass 1: x fp32 -> bf16 ----------------
__global__ void cvt_x_kernel(const float* __restrict__ x, bf16_t* __restrict__ xb, long n8) {
  const long stride = (long)gridDim.x * blockDim.x;
  for (long i = (long)blockIdx.x * blockDim.x + threadIdx.x; i < n8; i += stride) {
    const float4* p = reinterpret_cast<const float4*>(x + i * 8);
    const float4 f0 = p[0];
    const float4 f1 = p[1];
    bf16x8 o;
    o[0] = (bf16_t)f0.x; o[1] = (bf16_t)f0.y; o[2] = (bf16_t)f0.z; o[3] = (bf16_t)f0.w;
    o[4] = (bf16_t)f1.x; o[5] = (bf16_t)f1.y; o[6] = (bf16_t)f1.z; o[7] = (bf16_t)f1.w;
    *reinterpret_cast<bf16x8*>(xb + i * 8) = o;
  }
}

// ---------------- pre-pass 2: W int32(int4) * scale -> bf16 ----------------
__global__ void deq_w_kernel(const int* __restrict__ qw, const float* __restrict__ sc,
                             bf16_t* __restrict__ wb, int I, int G) {
  const int n = blockIdx.y;
  const int kb = blockIdx.x * blockDim.x + threadIdx.x;
  const int k = kb * 8;
  if (k >= I) return;
  const float s = sc[(size_t)n * (I / G) + k / G];
  const int4* qp = reinterpret_cast<const int4*>(qw + (size_t)n * I + k);
  const int4 q0 = qp[0];
  const int4 q1 = qp[1];
  bf16x8 o;
  o[0] = (bf16_t)((float)q0.x * s);
  o[1] = (bf16_t)((float)q0.y * s);
  o[2] = (bf16_t)((float)q0.z * s);
  o[3] = (bf16_t)((float)q0.w * s);
  o[4] = (bf16_t)((float)q1.x * s);
  o[5] = (bf16_t)((float)q1.y * s);
  o[6] = (bf16_t)((float)q1.z * s);
  o[7] = (bf16_t)((float)q1.w * s);
  *reinterpret_cast<bf16x8*>(wb + (size_t)n * I + k) = o;
}

// =================== 256x256 8-wave pipelined GEMM ===================
// LDS: ring of 8 slots x 16KB. Matrix-chunk u: even -> A[u/2], odd -> B[u/2].
// Chunk = 256 rows x 32 k (bf16), logical row stride 64B, slot(u) = u&7.
// Swizzle (involution, both sides): byte ^= ((byte>>7)&3)<<4 within a slot.
//   Read side: lane-constant fold into aBase/bBase.
//   Write side: LDS dest linear (global_load_lds), global SOURCE column permuted.
// Phase P: even P=2c computes MM(A[c]h0,B[c]), reads {B[c] (u=P+1), A[c]h1 (u=P)},
//   stages A[c+3] (u=P+6). Odd P=2c+1 computes MM(A[c]h1,B[c]), reads {A[c+1]h0
//   (u=P+1)}, stages B[c+3] (u=P+6). Invariant: WAITV(6) at phase Q guarantees
//   chunks u<=Q+2 landed (own wave); + end-of-phase barrier => at phase P all
//   reads (u<=P+1) are globally visible. WAR: slot of u reused at phase u+8-6=u+2
//   after last read of u drained (WAITL at phase u+1) + barrier.

#define WAITV(n) asm volatile("s_waitcnt vmcnt(" #n ")" ::: "memory")
#define WAITL(n) asm volatile("s_waitcnt lgkmcnt(" #n ")" ::: "memory")
#define BAR() __builtin_amdgcn_s_barrier()
#define SETP(n) __builtin_amdgcn_s_setprio(n)

#define RD_A(cs, h, SET) do { \
  const unsigned sl_ = ((unsigned)(2u * (unsigned)(cs)) & 7u) * 16384u + (unsigned)(h) * 4096u; \
  _Pragma("unroll") \
  for (int i_ = 0; i_ < 4; ++i_) \
    SET[i_] = *reinterpret_cast<const bf16x8*>(&ldsb[sl_ + aBase + (unsigned)i_ * 1024u]); \
} while (0)

#define RD_B(cs, SET) do { \
  const unsigned sl_ = ((unsigned)(2u * (unsigned)(cs) + 1u) & 7u) * 16384u; \
  _Pragma("unroll") \
  for (int j_ = 0; j_ < 4; ++j_) \
    SET[j_] = *reinterpret_cast<const bf16x8*>(&ldsb[sl_ + bBase + (unsigned)j_ * 1024u]); \
} while (0)

#define STG_A(cs) do { \
  const unsigned sl_ = ((unsigned)(2u * (unsigned)(cs)) & 7u) * 16384u + wOff; \
  __builtin_amdgcn_global_load_lds((const gmem_byte*)(aS0 + (size_t)(cs) * 32), (lds_byte*)&ldsb[sl_], 16, 0, 0); \
  __builtin_amdgcn_global_load_lds((const gmem_byte*)(aS1 + (size_t)(cs) * 32), (lds_byte*)&ldsb[sl_ + 1024u], 16, 0, 0); \
} while (0)

#define STG_B(cs) do { \
  const unsigned sl_ = ((unsigned)(2u * (unsigned)(cs) + 1u) & 7u) * 16384u + wOff; \
  __builtin_amdgcn_global_load_lds((const gmem_byte*)(bS0 + (size_t)(cs) * 32), (lds_byte*)&ldsb[sl_], 16, 0, 0); \
  __builtin_amdgcn_global_load_lds((const gmem_byte*)(bS1 + (size_t)(cs) * 32), (lds_byte*)&ldsb[sl_ + 1024u], 16, 0, 0); \
} while (0)

#define MM(ASET, BSET, HO) do { \
  _Pragma("unroll") \
  for (int i_ = 0; i_ < 4; ++i_) \
  _Pragma("unroll") \
  for (int j_ = 0; j_ < 4; ++j_) \
    acc[(HO) + i_][j_] = __builtin_amdgcn_mfma_f32_16x16x32_bf16(ASET[i_], BSET[j_], acc[(HO) + i_][j_], 0, 0, 0); \
} while (0)

__launch_bounds__(512, 2)
__global__ void gemm256_kernel(const bf16_t* __restrict__ A, const bf16_t* __restrict__ B,
                               const float* __restrict__ bias, float* __restrict__ C,
                               int M, int N, int K) {
  __shared__ __align__(16) unsigned char ldsb[8 * 16384];  // 128 KiB

  const int tid = threadIdx.x;
  const int lane = tid & 63;
  const int w = tid >> 6;       // 0..7
  const int wr = w >> 2;        // m-half 0..1
  const int wc = w & 3;         // n-quarter 0..3

  // T1: bijective XCD swizzle (MT % 8 == 0 path).
  const int MT = M >> 8;
  int mt, nt;
  const int bid = blockIdx.x;
  if ((MT & 7) == 0) {
    const int xcd = bid & 7, idx = bid >> 3;
    const int mpx = MT >> 3;
    nt = idx / mpx;
    mt = xcd * mpx + (idx - nt * mpx);
  } else {
    mt = bid % MT;
    nt = bid / MT;
  }
  const int m0 = mt << 8, n0 = nt << 8;

  // staging: per wave-instr 16 rows x 64B; lane -> row = w*32 + (l>>2) (+16),
  // LDS dest linear (lane*16). Global source column is swizzle-permuted:
  // col16 = (l&3) ^ ((l>>3)&3)  (within the same 64B row segment -> coalesced).
  const int srow = lane >> 2;
  const int scol = ((lane & 3) ^ ((lane >> 3) & 3)) * 8;  // bf16 units
  const bf16_t* aS0 = A + (size_t)(m0 + w * 32 + srow) * K + scol;
  const bf16_t* aS1 = aS0 + (size_t)16 * K;
  const bf16_t* bS0 = B + (size_t)(n0 + w * 32 + srow) * K + scol;
  const bf16_t* bS1 = bS0 + (size_t)16 * K;
  const unsigned wOff = (unsigned)w * 2048u;

  // frag addressing: lane reads logical (row = [wr*128|wc*64] + h*64 + i*16 + fr,
  // kbyte = (l>>4)*16); swizzle folds to lane-constant XOR of bits 5:4 with fr[2:1].
  const unsigned fr = lane & 15;
  const unsigned kbyte = ((unsigned)lane >> 4) * 16u;
  const unsigned swz = ((fr >> 1) & 3u) << 4;
  const unsigned aBase = ((unsigned)(wr * 128 + (int)fr) * 64u + kbyte) ^ swz;  // + h*4096 + i*1024
  const unsigned bBase = ((unsigned)(wc * 64 + (int)fr) * 64u + kbyte) ^ swz;   // + j*1024

  f32x4 acc[8][4];
  const f32x4 zero = {0.f, 0.f, 0.f, 0.f};
#pragma unroll
  for (int i = 0; i < 8; ++i)
#pragma unroll
    for (int j = 0; j < 4; ++j) acc[i][j] = zero;

  bf16x8 aA0[4], aA1[4], bB[4];

  const int NC = K >> 5;  // 32-wide K chunks

  // ---- prologue: stage u=0..5 (A0,B0,A1,B1,A2,B2) ----
  STG_A(0); STG_B(0); STG_A(1); STG_B(1); STG_A(2); STG_B(2);
  WAITV(8);           // A[0],B[0] landed (own wave)
  BAR();              // ... globally visible
  RD_A(0, 0, aA0);

  const int cFull = NC - 3;
  for (int c = 0; c < cFull; ++c) {
    // phase E (P=2c): reads u<=P+1; stage u=P+6
    WAITV(6); RD_B(c, bB); RD_A(c, 1, aA1); STG_A(c + 3);
    BAR(); WAITL(4);
    SETP(1); MM(aA0, bB, 0); SETP(0);
    BAR();
    // phase O (P=2c+1): reads u=P+1; stage u=P+6
    WAITV(6); RD_A(c + 1, 0, aA0); STG_B(c + 3);
    BAR(); WAITL(4);
    SETP(1); MM(aA1, bB, 4); SETP(0);
    BAR();
  }
  // tail c = NC-3: no stages; drain remaining loads once
  {
    const int c = NC - 3;
    WAITV(0); RD_B(c, bB); RD_A(c, 1, aA1);
    BAR(); WAITL(4); SETP(1); MM(aA0, bB, 0); SETP(0); BAR();
    RD_A(c + 1, 0, aA0);
    BAR(); WAITL(4); SETP(1); MM(aA1, bB, 4); SETP(0); BAR();
  }
  // tail c = NC-2
  {
    const int c = NC - 2;
    RD_B(c, bB); RD_A(c, 1, aA1);
    BAR(); WAITL(4); SETP(1); MM(aA0, bB, 0); SETP(0); BAR();
    RD_A(c + 1, 0, aA0);
    BAR(); WAITL(4); SETP(1); MM(aA1, bB, 4); SETP(0); BAR();
  }
  // tail c = NC-1
  {
    const int c = NC - 1;
    RD_B(c, bB); RD_A(c, 1, aA1);
    BAR(); WAITL(4); SETP(1); MM(aA0, bB, 0); SETP(0); BAR();
    WAITL(0);
    SETP(1); MM(aA1, bB, 4); SETP(0);
  }

  // epilogue: C/D layout col = lane&15 (n), row = (lane>>4)*4 + r (m)
  const int row0 = m0 + wr * 128 + ((lane >> 4) << 2);
  const int col0 = n0 + wc * 64 + (lane & 15);
#pragma unroll
  for (int j = 0; j < 4; ++j) {
    const int n = col0 + j * 16;
    const float bv = bias[n];
#pragma unroll
    for (int hi = 0; hi < 8; ++hi) {
      const int rbase = row0 + (hi >> 2) * 64 + (hi & 3) * 16;
#pragma unroll
      for (int r = 0; r < 4; ++r)
        C[(size_t)(rbase + r) * N + n] = acc[hi][j][r] + bv;
    }
  }
}

// ---------------- fallback: round-0 128x128 kernel (non-conforming shapes) ----------------
#define BM 128
#define BK 32
__launch_bounds__(256)
__global__ void gemm_bt_kernel(const bf16_t* __restrict__ A, const bf16_t* __restrict__ B,
                               const float* __restrict__ bias, float* __restrict__ C,
                               int M, int N, int K) {
  __shared__ __align__(16) bf16_t As[2][BM * BK];
  __shared__ __align__(16) bf16_t Bs[2][BM * BK];
  const int tid = threadIdx.x;
  const int lane = tid & 63;
  const int w = tid >> 6;
  const int wr = w >> 1;
  const int wc = w & 1;
  const int m0 = blockIdx.y * BM;
  const int n0 = blockIdx.x * BM;
  const int srow = lane >> 2;
  const int schunk = lane & 3;
  f32x4 acc[4][4];
  const f32x4 zero = {0.f, 0.f, 0.f, 0.f};
#pragma unroll
  for (int i = 0; i < 4; ++i)
#pragma unroll
    for (int j = 0; j < 4; ++j) acc[i][j] = zero;
  const int nt = K / BK;
  auto stage = [&](int t, int buf) {
    const int k0 = t * BK;
#pragma unroll
    for (int j = 0; j < 2; ++j) {
      const int row = w * 32 + j * 16;
      const bf16_t* ga = A + (size_t)(m0 + row + srow) * K + k0 + schunk * 8;
      __builtin_amdgcn_global_load_lds((const gmem_byte*)ga, (lds_byte*)&As[buf][row * BK], 16, 0, 0);
      const bf16_t* gb = B + (size_t)(n0 + row + srow) * K + k0 + schunk * 8;
      __builtin_amdgcn_global_load_lds((const gmem_byte*)gb, (lds_byte*)&Bs[buf][row * BK], 16, 0, 0);
    }
  };
  auto compute = [&](int buf) {
    bf16x8 af[4], bfr[4];
    const int fr2 = lane & 15;
    const int kc = (lane >> 4) * 8;
#pragma unroll
    for (int i = 0; i < 4; ++i) {
      af[i] = *reinterpret_cast<const bf16x8*>(&As[buf][(wr * 64 + i * 16 + fr2) * BK + kc]);
      bfr[i] = *reinterpret_cast<const bf16x8*>(&Bs[buf][(wc * 64 + i * 16 + fr2) * BK + kc]);
    }
#pragma unroll
    for (int i = 0; i < 4; ++i)
#pragma unroll
      for (int j = 0; j < 4; ++j)
        acc[i][j] = __builtin_amdgcn_mfma_f32_16x16x32_bf16(af[i], bfr[j], acc[i][j], 0, 0, 0);
  };
  stage(0, 0);
  __syncthreads();
  int cur = 0;
  for (int t = 0; t < nt - 1; ++t) {
    stage(t + 1, cur ^ 1);
    compute(cur);
    __syncthreads();
    cur ^= 1;
  }
  compute(cur);
#pragma unroll
  for (int j = 0; j < 4; ++j) {
    const int n = n0 + wc * 64 + j * 16 + (lane & 15);
    const float bv = bias[n];
#pragma unroll
    for (int i = 0; i < 4; ++i) {
      const int mbase = m0 + wr * 64 + i * 16 + (lane >> 4) * 4;
#pragma unroll
      for (int r = 0; r < 4; ++r)
        C[(size_t)(mbase + r) * N + n] = acc[i][j][r] + bv;
    }
  }
}

extern "C" void kernel_launch(void* const* d_in, const int* in_sizes, int n_in,
                              void* d_out, int out_size, void* d_ws, size_t ws_size,
                              hipStream_t stream) {
  const float* x = (const float*)d_in[0];
  const int* qw = (const int*)d_in[1];
  const float* sc = (const float*)d_in[2];
  const float* bias = (const float*)d_in[3];
  float* out = (float*)d_out;

  const long O = in_sizes[3];
  const long I = in_sizes[1] / O;        // 4096
  const long M = in_sizes[0] / I;        // 8192
  const long G = I / (in_sizes[2] / O);  // 128

  bf16_t* xb = (bf16_t*)d_ws;
  bf16_t* wb = xb + (size_t)M * I;
  const size_t need = ((size_t)M * I + (size_t)O * I) * sizeof(bf16_t);
  if (ws_size < need) return;

  cvt_x_kernel<<<2048, 256, 0, stream>>>(x, xb, M * I / 8);

  dim3 dgrid((unsigned)((I / 8 + 255) / 256), (unsigned)O);
  deq_w_kernel<<<dgrid, 256, 0, stream>>>(qw, sc, wb, (int)I, (int)G);

  const long NC = I >> 5;
  if ((M & 255) == 0 && (O & 255) == 0 && (I & 31) == 0 && NC >= 8) {
    const int nwg = (int)((M >> 8) * (O >> 8));
    gemm256_kernel<<<nwg, 512, 0, stream>>>(xb, wb, bias, out, (int)M, (int)O, (int)I);
  } else {
    dim3 ggrid((unsigned)(O / BM), (unsigned)(M / BM));
    gemm_bt_kernel<<<ggrid, 256, 0, stream>>>(xb, wb, bias, out, (int)M, (int)O, (int)I);
  }
}

// Round 4
// 813.715 us; speedup vs baseline: 1.4493x; 1.0222x over previous
//
#include <hip/hip_runtime.h>
#include <hip/hip_bf16.h>

// QuantizedLinear: y[M,N] = x[M,K] . W[N,K]^T + bias ; W = int4 * groupscale(G=128)
// Round 3: same 256x256 ring-8 GEMM, but phase re-timed so ds_reads (for phase
// P+1) issue after the publish barrier and drain UNDER phase P's MFMA cluster.

typedef __bf16 bf16_t;
typedef __bf16 bf16x8 __attribute__((ext_vector_type(8)));
typedef float f32x4 __attribute__((ext_vector_type(4)));
typedef __attribute__((address_space(3))) unsigned char lds_byte;
typedef __attribute__((address_space(1))) unsigned char gmem_byte;

// ---------------- pre-pass 1: x fp32 -> bf16 ----------------
__global__ void cvt_x_kernel(const float* __restrict__ x, bf16_t* __restrict__ xb, long n8) {
  const long stride = (long)gridDim.x * blockDim.x;
  for (long i = (long)blockIdx.x * blockDim.x + threadIdx.x; i < n8; i += stride) {
    const float4* p = reinterpret_cast<const float4*>(x + i * 8);
    const float4 f0 = p[0];
    const float4 f1 = p[1];
    bf16x8 o;
    o[0] = (bf16_t)f0.x; o[1] = (bf16_t)f0.y; o[2] = (bf16_t)f0.z; o[3] = (bf16_t)f0.w;
    o[4] = (bf16_t)f1.x; o[5] = (bf16_t)f1.y; o[6] = (bf16_t)f1.z; o[7] = (bf16_t)f1.w;
    *reinterpret_cast<bf16x8*>(xb + i * 8) = o;
  }
}

// ---------------- pre-pass 2: W int32(int4) * scale -> bf16 ----------------
__global__ void deq_w_kernel(const int* __restrict__ qw, const float* __restrict__ sc,
                             bf16_t* __restrict__ wb, int I, int G) {
  const int n = blockIdx.y;
  const int kb = blockIdx.x * blockDim.x + threadIdx.x;
  const int k = kb * 8;
  if (k >= I) return;
  const float s = sc[(size_t)n * (I / G) + k / G];
  const int4* qp = reinterpret_cast<const int4*>(qw + (size_t)n * I + k);
  const int4 q0 = qp[0];
  const int4 q1 = qp[1];
  bf16x8 o;
  o[0] = (bf16_t)((float)q0.x * s);
  o[1] = (bf16_t)((float)q0.y * s);
  o[2] = (bf16_t)((float)q0.z * s);
  o[3] = (bf16_t)((float)q0.w * s);
  o[4] = (bf16_t)((float)q1.x * s);
  o[5] = (bf16_t)((float)q1.y * s);
  o[6] = (bf16_t)((float)q1.z * s);
  o[7] = (bf16_t)((float)q1.w * s);
  *reinterpret_cast<bf16x8*>(wb + (size_t)n * I + k) = o;
}

// =================== 256x256 8-wave pipelined GEMM ===================
// LDS ring of 8 slots x 16KB; matrix-chunk u: even=A[u/2], odd=B[u/2]; slot=u&7;
// u staged at phase u-6 (even phases stage A, odd stage B).
// Phase P: WAITV(6) [own stages <=P-4 landed] ; STG(u=P+6) ; BAR [publishes
// <=P+2... conservatively <=P-4+6; reads below touch u<=P+2, staged <=P-4 ✓];
// RD(operands for phase P+1, u<=P+2); SETPRIO MM(phase P operands) ; WAITL(0)
// [reads complete before end-bar => WAR-safe vs overwrite at phase u+2] ; BAR.
// B frags double-buffered (bB0/bB1); aA1 read even-phase, used odd-phase.

#define WAITV(n) asm volatile("s_waitcnt vmcnt(" #n ")" ::: "memory")
#define WAITL(n) asm volatile("s_waitcnt lgkmcnt(" #n ")" ::: "memory")
#define BAR() __builtin_amdgcn_s_barrier()
#define SETP(n) __builtin_amdgcn_s_setprio(n)

#define RD_A(cs, h, SET) do { \
  const unsigned sl_ = ((unsigned)(2u * (unsigned)(cs)) & 7u) * 16384u + (unsigned)(h) * 4096u; \
  _Pragma("unroll") \
  for (int i_ = 0; i_ < 4; ++i_) \
    SET[i_] = *reinterpret_cast<const bf16x8*>(&ldsb[sl_ + aBase + (unsigned)i_ * 1024u]); \
} while (0)

#define RD_B(cs, SET) do { \
  const unsigned sl_ = ((unsigned)(2u * (unsigned)(cs) + 1u) & 7u) * 16384u; \
  _Pragma("unroll") \
  for (int j_ = 0; j_ < 4; ++j_) \
    SET[j_] = *reinterpret_cast<const bf16x8*>(&ldsb[sl_ + bBase + (unsigned)j_ * 1024u]); \
} while (0)

#define STG_A(cs) do { \
  const unsigned sl_ = ((unsigned)(2u * (unsigned)(cs)) & 7u) * 16384u + wOff; \
  __builtin_amdgcn_global_load_lds((const gmem_byte*)(aS0 + (size_t)(cs) * 32), (lds_byte*)&ldsb[sl_], 16, 0, 0); \
  __builtin_amdgcn_global_load_lds((const gmem_byte*)(aS1 + (size_t)(cs) * 32), (lds_byte*)&ldsb[sl_ + 1024u], 16, 0, 0); \
} while (0)

#define STG_B(cs) do { \
  const unsigned sl_ = ((unsigned)(2u * (unsigned)(cs) + 1u) & 7u) * 16384u + wOff; \
  __builtin_amdgcn_global_load_lds((const gmem_byte*)(bS0 + (size_t)(cs) * 32), (lds_byte*)&ldsb[sl_], 16, 0, 0); \
  __builtin_amdgcn_global_load_lds((const gmem_byte*)(bS1 + (size_t)(cs) * 32), (lds_byte*)&ldsb[sl_ + 1024u], 16, 0, 0); \
} while (0)

#define MM(ASET, BSET, HO) do { \
  _Pragma("unroll") \
  for (int i_ = 0; i_ < 4; ++i_) \
  _Pragma("unroll") \
  for (int j_ = 0; j_ < 4; ++j_) \
    acc[(HO) + i_][j_] = __builtin_amdgcn_mfma_f32_16x16x32_bf16(ASET[i_], BSET[j_], acc[(HO) + i_][j_], 0, 0, 0); \
} while (0)

__launch_bounds__(512, 2)
__global__ void gemm256_kernel(const bf16_t* __restrict__ A, const bf16_t* __restrict__ B,
                               const float* __restrict__ bias, float* __restrict__ C,
                               int M, int N, int K) {
  __shared__ __align__(16) unsigned char ldsb[8 * 16384];  // 128 KiB

  const int tid = threadIdx.x;
  const int lane = tid & 63;
  const int w = tid >> 6;       // 0..7
  const int wr = w >> 2;        // m-half 0..1
  const int wc = w & 3;         // n-quarter 0..3

  // T1: bijective XCD swizzle (MT % 8 == 0 path).
  const int MT = M >> 8;
  int mt, nt;
  const int bid = blockIdx.x;
  if ((MT & 7) == 0) {
    const int xcd = bid & 7, idx = bid >> 3;
    const int mpx = MT >> 3;
    nt = idx / mpx;
    mt = xcd * mpx + (idx - nt * mpx);
  } else {
    mt = bid % MT;
    nt = bid / MT;
  }
  const int m0 = mt << 8, n0 = nt << 8;

  // staging: LDS dest linear; global SOURCE column swizzle-permuted (involution
  // byte ^= ((byte>>7)&3)<<4, folded to col16 = (l&3) ^ ((l>>3)&3)).
  const int srow = lane >> 2;
  const int scol = ((lane & 3) ^ ((lane >> 3) & 3)) * 8;  // bf16 units
  const bf16_t* aS0 = A + (size_t)(m0 + w * 32 + srow) * K + scol;
  const bf16_t* aS1 = aS0 + (size_t)16 * K;
  const bf16_t* bS0 = B + (size_t)(n0 + w * 32 + srow) * K + scol;
  const bf16_t* bS1 = bS0 + (size_t)16 * K;
  const unsigned wOff = (unsigned)w * 2048u;

  // frag read addressing with the same swizzle folded in (lane-constant XOR).
  const unsigned fr = lane & 15;
  const unsigned kbyte = ((unsigned)lane >> 4) * 16u;
  const unsigned swz = ((fr >> 1) & 3u) << 4;
  const unsigned aBase = ((unsigned)(wr * 128 + (int)fr) * 64u + kbyte) ^ swz;  // + h*4096 + i*1024
  const unsigned bBase = ((unsigned)(wc * 64 + (int)fr) * 64u + kbyte) ^ swz;   // + j*1024

  f32x4 acc[8][4];
  const f32x4 zero = {0.f, 0.f, 0.f, 0.f};
#pragma unroll
  for (int i = 0; i < 8; ++i)
#pragma unroll
    for (int j = 0; j < 4; ++j) acc[i][j] = zero;

  bf16x8 aA00[4], aA01[4], aA1[4], bB0[4], bB1[4];

  const int NC = K >> 5;  // 32-wide K chunks (even, >=8; guarded at launch)

  // ---- prologue: stage u=0..5; read chunk-0 operands ----
  STG_A(0); STG_B(0); STG_A(1); STG_B(1); STG_A(2); STG_B(2);
  WAITV(8);            // u=0,1 landed (own wave)
  BAR();               // published
  RD_A(0, 0, aA00);
  RD_B(0, bB0);

  const int mainPairs = (NC - 4) >> 1;   // chunks 0 .. NC-5 in pairs
  for (int cc = 0; cc < mainPairs; ++cc) {
    const int c0 = 2 * cc, c1 = 2 * cc + 1;
    // ---- chunk c0 (set0: aA00,bB0) ----
    WAITV(6); STG_A(c0 + 3); BAR();
    RD_A(c0, 1, aA1);
    SETP(1); MM(aA00, bB0, 0); SETP(0);
    WAITL(0); BAR();
    WAITV(6); STG_B(c0 + 3); BAR();
    RD_A(c0 + 1, 0, aA01); RD_B(c0 + 1, bB1);
    SETP(1); MM(aA1, bB0, 4); SETP(0);
    WAITL(0); BAR();
    // ---- chunk c1 (set1: aA01,bB1) ----
    WAITV(6); STG_A(c1 + 3); BAR();
    RD_A(c1, 1, aA1);
    SETP(1); MM(aA01, bB1, 0); SETP(0);
    WAITL(0); BAR();
    WAITV(6); STG_B(c1 + 3); BAR();
    RD_A(c1 + 1, 0, aA00); RD_B(c1 + 1, bB0);
    SETP(1); MM(aA1, bB1, 4); SETP(0);
    WAITL(0); BAR();
  }
  // ---- chunk NC-4 (set0), stages the last chunks (A[NC-1], B[NC-1]) ----
  {
    const int c = NC - 4;
    WAITV(6); STG_A(c + 3); BAR();
    RD_A(c, 1, aA1);
    SETP(1); MM(aA00, bB0, 0); SETP(0);
    WAITL(0); BAR();
    WAITV(6); STG_B(c + 3); BAR();
    RD_A(c + 1, 0, aA01); RD_B(c + 1, bB1);
    SETP(1); MM(aA1, bB0, 4); SETP(0);
    WAITL(0); BAR();
  }
  // ---- tail: chunks NC-3 (set1), NC-2 (set0), NC-1 (set1); no more staging ----
  {
    const int c = NC - 3;
    WAITV(0); BAR();   // everything landed + published; no further LDS writes
    RD_A(c, 1, aA1);
    SETP(1); MM(aA01, bB1, 0); SETP(0);
    RD_A(c + 1, 0, aA00); RD_B(c + 1, bB0);
    SETP(1); MM(aA1, bB1, 4); SETP(0);
    RD_A(c + 1, 1, aA1);
    SETP(1); MM(aA00, bB0, 0); SETP(0);
    RD_A(c + 2, 0, aA01); RD_B(c + 2, bB1);
    SETP(1); MM(aA1, bB0, 4); SETP(0);
    RD_A(c + 2, 1, aA1);
    SETP(1); MM(aA01, bB1, 0); SETP(0);
    SETP(1); MM(aA1, bB1, 4); SETP(0);
  }

  // epilogue: C/D layout col = lane&15 (n), row = (lane>>4)*4 + r (m)
  const int row0 = m0 + wr * 128 + ((lane >> 4) << 2);
  const int col0 = n0 + wc * 64 + (lane & 15);
#pragma unroll
  for (int j = 0; j < 4; ++j) {
    const int n = col0 + j * 16;
    const float bv = bias[n];
#pragma unroll
    for (int hi = 0; hi < 8; ++hi) {
      const int rbase = row0 + (hi >> 2) * 64 + (hi & 3) * 16;
#pragma unroll
      for (int r = 0; r < 4; ++r)
        C[(size_t)(rbase + r) * N + n] = acc[hi][j][r] + bv;
    }
  }
}

// ---------------- fallback: round-0 128x128 kernel (non-conforming shapes) ----------------
#define BM 128
#define BK 32
__launch_bounds__(256)
__global__ void gemm_bt_kernel(const bf16_t* __restrict__ A, const bf16_t* __restrict__ B,
                               const float* __restrict__ bias, float* __restrict__ C,
                               int M, int N, int K) {
  __shared__ __align__(16) bf16_t As[2][BM * BK];
  __shared__ __align__(16) bf16_t Bs[2][BM * BK];
  const int tid = threadIdx.x;
  const int lane = tid & 63;
  const int w = tid >> 6;
  const int wr = w >> 1;
  const int wc = w & 1;
  const int m0 = blockIdx.y * BM;
  const int n0 = blockIdx.x * BM;
  const int srow = lane >> 2;
  const int schunk = lane & 3;
  f32x4 acc[4][4];
  const f32x4 zero = {0.f, 0.f, 0.f, 0.f};
#pragma unroll
  for (int i = 0; i < 4; ++i)
#pragma unroll
    for (int j = 0; j < 4; ++j) acc[i][j] = zero;
  const int nt = K / BK;
  auto stage = [&](int t, int buf) {
    const int k0 = t * BK;
#pragma unroll
    for (int j = 0; j < 2; ++j) {
      const int row = w * 32 + j * 16;
      const bf16_t* ga = A + (size_t)(m0 + row + srow) * K + k0 + schunk * 8;
      __builtin_amdgcn_global_load_lds((const gmem_byte*)ga, (lds_byte*)&As[buf][row * BK], 16, 0, 0);
      const bf16_t* gb = B + (size_t)(n0 + row + srow) * K + k0 + schunk * 8;
      __builtin_amdgcn_global_load_lds((const gmem_byte*)gb, (lds_byte*)&Bs[buf][row * BK], 16, 0, 0);
    }
  };
  auto compute = [&](int buf) {
    bf16x8 af[4], bfr[4];
    const int fr2 = lane & 15;
    const int kc = (lane >> 4) * 8;
#pragma unroll
    for (int i = 0; i < 4; ++i) {
      af[i] = *reinterpret_cast<const bf16x8*>(&As[buf][(wr * 64 + i * 16 + fr2) * BK + kc]);
      bfr[i] = *reinterpret_cast<const bf16x8*>(&Bs[buf][(wc * 64 + i * 16 + fr2) * BK + kc]);
    }
#pragma unroll
    for (int i = 0; i < 4; ++i)
#pragma unroll
      for (int j = 0; j < 4; ++j)
        acc[i][j] = __builtin_amdgcn_mfma_f32_16x16x32_bf16(af[i], bfr[j], acc[i][j], 0, 0, 0);
  };
  stage(0, 0);
  __syncthreads();
  int cur = 0;
  for (int t = 0; t < nt - 1; ++t) {
    stage(t + 1, cur ^ 1);
    compute(cur);
    __syncthreads();
    cur ^= 1;
  }
  compute(cur);
#pragma unroll
  for (int j = 0; j < 4; ++j) {
    const int n = n0 + wc * 64 + j * 16 + (lane & 15);
    const float bv = bias[n];
#pragma unroll
    for (int i = 0; i < 4; ++i) {
      const int mbase = m0 + wr * 64 + i * 16 + (lane >> 4) * 4;
#pragma unroll
      for (int r = 0; r < 4; ++r)
        C[(size_t)(mbase + r) * N + n] = acc[i][j][r] + bv;
    }
  }
}

extern "C" void kernel_launch(void* const* d_in, const int* in_sizes, int n_in,
                              void* d_out, int out_size, void* d_ws, size_t ws_size,
                              hipStream_t stream) {
  const float* x = (const float*)d_in[0];
  const int* qw = (const int*)d_in[1];
  const float* sc = (const float*)d_in[2];
  const float* bias = (const float*)d_in[3];
  float* out = (float*)d_out;

  const long O = in_sizes[3];
  const long I = in_sizes[1] / O;        // 4096
  const long M = in_sizes[0] / I;        // 8192
  const long G = I / (in_sizes[2] / O);  // 128

  bf16_t* xb = (bf16_t*)d_ws;
  bf16_t* wb = xb + (size_t)M * I;
  const size_t need = ((size_t)M * I + (size_t)O * I) * sizeof(bf16_t);
  if (ws_size < need) return;

  cvt_x_kernel<<<2048, 256, 0, stream>>>(x, xb, M * I / 8);

  dim3 dgrid((unsigned)((I / 8 + 255) / 256), (unsigned)O);
  deq_w_kernel<<<dgrid, 256, 0, stream>>>(qw, sc, wb, (int)I, (int)G);

  const long NC = I >> 5;
  if ((M & 255) == 0 && (O & 255) == 0 && (I & 31) == 0 && NC >= 8 && (NC & 1) == 0) {
    const int nwg = (int)((M >> 8) * (O >> 8));
    gemm256_kernel<<<nwg, 512, 0, stream>>>(xb, wb, bias, out, (int)M, (int)O, (int)I);
  } else {
    dim3 ggrid((unsigned)(O / BM), (unsigned)(M / BM));
    gemm_bt_kernel<<<ggrid, 256, 0, stream>>>(xb, wb, bias, out, (int)M, (int)O, (int)I);
  }
}

// Round 6
// 776.313 us; speedup vs baseline: 1.5191x; 1.0482x over previous
//
#include <hip/hip_runtime.h>
#include <hip/hip_bf16.h>

// QuantizedLinear: y[M,N] = x[M,K] . W[N,K]^T + bias ; W = int4 * groupscale(G=128)
// Round 5: 8-phase m201-style schedule with corrected stage/read hazard table.
// All B reads at phase tops p1/p5; stage order p1:d1.A1(t+1), p2:d0.B0(t+2),
// p3:d0.B1(t+2), p4:d0.A0(t+2)+vmcnt(6), p5:d0.A1(t+2), p6:d1.B0(t+3),
// p7:d1.B1(t+3), p8:d1.A0(t+3)+vmcnt(6). Every overwrite >=1 barrier after the
// slot's last ds_read drains; vmcnt(6)@p4 publishes tile t+1, @p8 tile t+2.

typedef __bf16 bf16_t;
typedef __bf16 bf16x8 __attribute__((ext_vector_type(8)));
typedef float f32x4 __attribute__((ext_vector_type(4)));
typedef __attribute__((address_space(3))) unsigned char lds_byte;
typedef __attribute__((address_space(1))) unsigned char gmem_byte;

// ---------------- pre-pass 1: x fp32 -> bf16 ----------------
__global__ void cvt_x_kernel(const float* __restrict__ x, bf16_t* __restrict__ xb, long n8) {
  const long stride = (long)gridDim.x * blockDim.x;
  for (long i = (long)blockIdx.x * blockDim.x + threadIdx.x; i < n8; i += stride) {
    const float4* p = reinterpret_cast<const float4*>(x + i * 8);
    const float4 f0 = p[0];
    const float4 f1 = p[1];
    bf16x8 o;
    o[0] = (bf16_t)f0.x; o[1] = (bf16_t)f0.y; o[2] = (bf16_t)f0.z; o[3] = (bf16_t)f0.w;
    o[4] = (bf16_t)f1.x; o[5] = (bf16_t)f1.y; o[6] = (bf16_t)f1.z; o[7] = (bf16_t)f1.w;
    *reinterpret_cast<bf16x8*>(xb + i * 8) = o;
  }
}

// ---------------- pre-pass 2: W int32(int4) * scale -> bf16 ----------------
__global__ void deq_w_kernel(const int* __restrict__ qw, const float* __restrict__ sc,
                             bf16_t* __restrict__ wb, int I, int G) {
  const int n = blockIdx.y;
  const int kb = blockIdx.x * blockDim.x + threadIdx.x;
  const int k = kb * 8;
  if (k >= I) return;
  const float s = sc[(size_t)n * (I / G) + k / G];
  const int4* qp = reinterpret_cast<const int4*>(qw + (size_t)n * I + k);
  const int4 q0 = qp[0];
  const int4 q1 = qp[1];
  bf16x8 o;
  o[0] = (bf16_t)((float)q0.x * s);
  o[1] = (bf16_t)((float)q0.y * s);
  o[2] = (bf16_t)((float)q0.z * s);
  o[3] = (bf16_t)((float)q0.w * s);
  o[4] = (bf16_t)((float)q1.x * s);
  o[5] = (bf16_t)((float)q1.y * s);
  o[6] = (bf16_t)((float)q1.z * s);
  o[7] = (bf16_t)((float)q1.w * s);
  *reinterpret_cast<bf16x8*>(wb + (size_t)n * I + k) = o;
}

// =================== 256x256 8-wave 8-phase GEMM ===================
// LDS 128KB: dbuf d0 at 0 / d1 at +64K; halves A0(+0) A1(+16K) B0(+32K) B1(+48K).
// Half = 128 rows x 64 k bf16, row stride 128B; XOR swizzle: 16B-slot ^= (row&7)
// (write side: LDS dest linear for global_load_lds, global source col permuted;
// read side: lane-constant fold).
// Reads: p1: d0{Aq0, B nh0, B nh1}  p3: d0{Aq1}  p5: d1{Aq0,B both}  p7: d1{Aq1}.

#define WAITV(n) asm volatile("s_waitcnt vmcnt(" #n ")" ::: "memory")
#define WAITL(n) asm volatile("s_waitcnt lgkmcnt(" #n ")" ::: "memory")
#define BAR() __builtin_amdgcn_s_barrier()
#define SETP(n) __builtin_amdgcn_s_setprio(n)

// read A quadrant q (rows q*64..q*64+63 of this wave's wr-half) from dbuf DB
#define RD_A(DB, q) do { \
  _Pragma("unroll") \
  for (int i_ = 0; i_ < 4; ++i_) { \
    aF[i_][0] = *reinterpret_cast<const bf16x8*>(&ldsb[(DB) + aRd + (unsigned)((q) * 64 + i_ * 16) * 128u + ks0]); \
    aF[i_][1] = *reinterpret_cast<const bf16x8*>(&ldsb[(DB) + aRd + (unsigned)((q) * 64 + i_ * 16) * 128u + ks1]); \
  } \
} while (0)

// read B n-half nh (cols nh*32..+31 of this wave's 64-col strip) from dbuf DB
#define RD_B(DB, nh, BF) do { \
  _Pragma("unroll") \
  for (int j_ = 0; j_ < 2; ++j_) { \
    BF[j_][0] = *reinterpret_cast<const bf16x8*>(&ldsb[(DB) + bRd + (unsigned)((nh) * 32 + j_ * 16) * 128u + ks0]); \
    BF[j_][1] = *reinterpret_cast<const bf16x8*>(&ldsb[(DB) + bRd + (unsigned)((nh) * 32 + j_ * 16) * 128u + ks1]); \
  } \
} while (0)

// stage one 16KB half-tile (tile index tau): 2 global_load_lds per thread
#define STG(BASE, P, tau) do { \
  __builtin_amdgcn_global_load_lds((const gmem_byte*)((P) + (size_t)(tau) * 64), \
                                   (lds_byte*)&ldsb[(BASE) + wOff], 16, 0, 0); \
  __builtin_amdgcn_global_load_lds((const gmem_byte*)((P) + (size_t)64 * K + (size_t)(tau) * 64), \
                                   (lds_byte*)&ldsb[(BASE) + 8192u + wOff], 16, 0, 0); \
} while (0)

// 16 MFMA: C-quadrant (q, nh) x K=64 (s=0,1)
#define MMQ(q, nh, BF) do { \
  _Pragma("unroll") \
  for (int i_ = 0; i_ < 4; ++i_) \
  _Pragma("unroll") \
  for (int j_ = 0; j_ < 2; ++j_) { \
    acc[(q) * 4 + i_][(nh) * 2 + j_] = __builtin_amdgcn_mfma_f32_16x16x32_bf16(aF[i_][0], BF[j_][0], acc[(q) * 4 + i_][(nh) * 2 + j_], 0, 0, 0); \
    acc[(q) * 4 + i_][(nh) * 2 + j_] = __builtin_amdgcn_mfma_f32_16x16x32_bf16(aF[i_][1], BF[j_][1], acc[(q) * 4 + i_][(nh) * 2 + j_], 0, 0, 0); \
  } \
} while (0)

__launch_bounds__(512, 2)
__global__ void gemm256_kernel(const bf16_t* __restrict__ A, const bf16_t* __restrict__ B,
                               const float* __restrict__ bias, float* __restrict__ C,
                               int M, int N, int K) {
  __shared__ __align__(16) unsigned char ldsb[131072];

  const int tid = threadIdx.x;
  const int lane = tid & 63;
  const int w = tid >> 6;       // 0..7
  const int wr = w >> 2;        // m-half
  const int wc = w & 3;         // n-quarter

  // T1: bijective XCD swizzle (MT % 8 == 0 path).
  const int MT = M >> 8;
  int mt, nt;
  const int bid = blockIdx.x;
  if ((MT & 7) == 0) {
    const int xcd = bid & 7, idx = bid >> 3;
    const int mpx = MT >> 3;
    nt = idx / mpx;
    mt = xcd * mpx + (idx - nt * mpx);
  } else {
    mt = bid % MT;
    nt = bid / MT;
  }
  const int m0 = mt << 8, n0 = nt << 8;

  // ---- staging addressing (linear LDS dest, pre-swizzled global source) ----
  // dest row = w*8 + (lane>>3) (+64 for 2nd load); phys 16B-slot = lane&7;
  // content slot = phys ^ (row&7) -> lane-constant source column.
  const int srow8 = lane >> 3;
  const int scol16 = (lane & 7) ^ (srow8 & 7);
  const bf16_t* aP0 = A + (size_t)(m0 + w * 8 + srow8) * K + scol16 * 8;
  const bf16_t* aP1 = aP0 + (size_t)128 * K;
  const bf16_t* bP0 = B + (size_t)(n0 + w * 8 + srow8) * K + scol16 * 8;
  const bf16_t* bP1 = bP0 + (size_t)128 * K;
  const unsigned wOff = (unsigned)w * 1024u;

  // ---- fragment read addressing (swizzle folded, lane-constant) ----
  const unsigned fr = lane & 15;
  const unsigned hi16 = (unsigned)lane >> 4;
  const unsigned sw = (fr & 7u) << 4;
  const unsigned ks0 = (hi16 * 16u) ^ sw;          // k 0..31 chunk
  const unsigned ks1 = (64u + hi16 * 16u) ^ sw;    // k 32..63 chunk
  const unsigned aRd = (unsigned)wr * 16384u + fr * 128u;
  const unsigned bRd = 32768u + (unsigned)(wc >> 1) * 16384u +
                       ((unsigned)(wc & 1) * 64u + fr) * 128u;

  f32x4 acc[8][4];
  const f32x4 zero = {0.f, 0.f, 0.f, 0.f};
#pragma unroll
  for (int i = 0; i < 8; ++i)
#pragma unroll
    for (int j = 0; j < 4; ++j) acc[i][j] = zero;

  bf16x8 aF[4][2], bF0[2][2], bF1[2][2];

  const int NITER = K >> 7;  // 2 K-tiles (BK=64) per iteration; NITER >= 2 guarded

  // ---- prologue: d0 = tile0 {A0,B0,B1,A1}; d1 = tile1 {B0,B1,A0} ----
  STG(0u, aP0, 0); STG(32768u, bP0, 0); STG(49152u, bP1, 0); STG(16384u, aP1, 0);
  STG(98304u, bP0, 1); STG(114688u, bP1, 1); STG(65536u, aP0, 1);
  WAITV(6);  // tile0's 8 loads landed (own wave); carry-out = 6 (d1 halves)
  BAR();     // published

  for (int it = 0; it < NITER - 1; ++it) {
    const int t = 2 * it;
    // p1: compute d0 (q0,nh0); read d0 Aq0 + B both; stage d1.A1(t+1)
    RD_A(0u, 0); RD_B(0u, 0, bF0); RD_B(0u, 1, bF1); STG(81920u, aP1, t + 1);
    BAR(); WAITL(0);
    SETP(1); MMQ(0, 0, bF0); SETP(0); BAR();
    // p2: (q0,nh1); stage d0.B0(t+2)  [d0.B last read: p1]
    STG(32768u, bP0, t + 2);
    BAR();
    SETP(1); MMQ(0, 1, bF1); SETP(0); BAR();
    // p3: (q1,nh0); read d0 Aq1; stage d0.B1(t+2)
    RD_A(0u, 1); STG(49152u, bP1, t + 2);
    BAR(); WAITL(0);
    SETP(1); MMQ(1, 0, bF0); SETP(0); BAR();
    // p4: (q1,nh1); stage d0.A0(t+2) [d0.A last read: p3]; publish tile t+1
    STG(0u, aP0, t + 2); WAITV(6);
    BAR();
    SETP(1); MMQ(1, 1, bF1); SETP(0); BAR();
    // p5: compute d1 (q0,nh0); read d1 Aq0 + B both; stage d0.A1(t+2)
    RD_A(65536u, 0); RD_B(65536u, 0, bF0); RD_B(65536u, 1, bF1); STG(16384u, aP1, t + 2);
    BAR(); WAITL(0);
    SETP(1); MMQ(0, 0, bF0); SETP(0); BAR();
    // p6: (q0,nh1); stage d1.B0(t+3)  [d1.B last read: p5]
    STG(98304u, bP0, t + 3);
    BAR();
    SETP(1); MMQ(0, 1, bF1); SETP(0); BAR();
    // p7: (q1,nh0); read d1 Aq1; stage d1.B1(t+3)
    RD_A(65536u, 1); STG(114688u, bP1, t + 3);
    BAR(); WAITL(0);
    SETP(1); MMQ(1, 0, bF0); SETP(0); BAR();
    // p8: (q1,nh1); stage d1.A0(t+3) [d1.A last read: p7]; publish d0 tile t+2
    STG(65536u, aP0, t + 3); WAITV(6);
    BAR();
    SETP(1); MMQ(1, 1, bF1); SETP(0); BAR();
  }
  // ---- last iteration (t = 2*NITER-2): only p1's stage; drain at p4 ----
  {
    const int t = 2 * NITER - 2;
    RD_A(0u, 0); RD_B(0u, 0, bF0); RD_B(0u, 1, bF1); STG(81920u, aP1, t + 1);
    BAR(); WAITL(0);
    SETP(1); MMQ(0, 0, bF0); SETP(0); BAR();
    BAR();
    SETP(1); MMQ(0, 1, bF1); SETP(0); BAR();
    RD_A(0u, 1);
    BAR(); WAITL(0);
    SETP(1); MMQ(1, 0, bF0); SETP(0); BAR();
    WAITV(0);   // drain carry-in d1 halves + p1's A1 stage
    BAR();
    SETP(1); MMQ(1, 1, bF1); SETP(0); BAR();
    // d1 tile t+1 fully resident & published; no further LDS writes anywhere.
    RD_A(65536u, 0); RD_B(65536u, 0, bF0); RD_B(65536u, 1, bF1);
    WAITL(0);
    SETP(1); MMQ(0, 0, bF0); SETP(0);
    SETP(1); MMQ(0, 1, bF1); SETP(0);
    RD_A(65536u, 1);
    WAITL(0);
    SETP(1); MMQ(1, 0, bF0); SETP(0);
    SETP(1); MMQ(1, 1, bF1); SETP(0);
  }

  // epilogue: C/D layout col = lane&15 (n), row = (lane>>4)*4 + r (m)
  const int row0 = m0 + wr * 128 + ((lane >> 4) << 2);
  const int col0 = n0 + wc * 64 + (lane & 15);
#pragma unroll
  for (int j = 0; j < 4; ++j) {
    const int n = col0 + j * 16;
    const float bv = bias[n];
#pragma unroll
    for (int hi = 0; hi < 8; ++hi) {
      const int rbase = row0 + (hi >> 2) * 64 + (hi & 3) * 16;
#pragma unroll
      for (int r = 0; r < 4; ++r)
        C[(size_t)(rbase + r) * N + n] = acc[hi][j][r] + bv;
    }
  }
}

// ---------------- fallback: 128x128 kernel (non-conforming shapes) ----------------
#define BM 128
#define BK 32
__launch_bounds__(256)
__global__ void gemm_bt_kernel(const bf16_t* __restrict__ A, const bf16_t* __restrict__ B,
                               const float* __restrict__ bias, float* __restrict__ C,
                               int M, int N, int K) {
  __shared__ __align__(16) bf16_t As[2][BM * BK];
  __shared__ __align__(16) bf16_t Bs[2][BM * BK];
  const int tid = threadIdx.x;
  const int lane = tid & 63;
  const int w = tid >> 6;
  const int wr = w >> 1;
  const int wc = w & 1;
  const int m0 = blockIdx.y * BM;
  const int n0 = blockIdx.x * BM;
  const int srow = lane >> 2;
  const int schunk = lane & 3;
  f32x4 acc[4][4];
  const f32x4 zero = {0.f, 0.f, 0.f, 0.f};
#pragma unroll
  for (int i = 0; i < 4; ++i)
#pragma unroll
    for (int j = 0; j < 4; ++j) acc[i][j] = zero;
  const int nt = K / BK;
  auto stage = [&](int t, int buf) {
    const int k0 = t * BK;
#pragma unroll
    for (int j = 0; j < 2; ++j) {
      const int row = w * 32 + j * 16;
      const bf16_t* ga = A + (size_t)(m0 + row + srow) * K + k0 + schunk * 8;
      __builtin_amdgcn_global_load_lds((const gmem_byte*)ga, (lds_byte*)&As[buf][row * BK], 16, 0, 0);
      const bf16_t* gb = B + (size_t)(n0 + row + srow) * K + k0 + schunk * 8;
      __builtin_amdgcn_global_load_lds((const gmem_byte*)gb, (lds_byte*)&Bs[buf][row * BK], 16, 0, 0);
    }
  };
  auto compute = [&](int buf) {
    bf16x8 af[4], bfr[4];
    const int fr2 = lane & 15;
    const int kc = (lane >> 4) * 8;
#pragma unroll
    for (int i = 0; i < 4; ++i) {
      af[i] = *reinterpret_cast<const bf16x8*>(&As[buf][(wr * 64 + i * 16 + fr2) * BK + kc]);
      bfr[i] = *reinterpret_cast<const bf16x8*>(&Bs[buf][(wc * 64 + i * 16 + fr2) * BK + kc]);
    }
#pragma unroll
    for (int i = 0; i < 4; ++i)
#pragma unroll
      for (int j = 0; j < 4; ++j)
        acc[i][j] = __builtin_amdgcn_mfma_f32_16x16x32_bf16(af[i], bfr[j], acc[i][j], 0, 0, 0);
  };
  stage(0, 0);
  __syncthreads();
  int cur = 0;
  for (int t = 0; t < nt - 1; ++t) {
    stage(t + 1, cur ^ 1);
    compute(cur);
    __syncthreads();
    cur ^= 1;
  }
  compute(cur);
#pragma unroll
  for (int j = 0; j < 4; ++j) {
    const int n = n0 + wc * 64 + j * 16 + (lane & 15);
    const float bv = bias[n];
#pragma unroll
    for (int i = 0; i < 4; ++i) {
      const int mbase = m0 + wr * 64 + i * 16 + (lane >> 4) * 4;
#pragma unroll
      for (int r = 0; r < 4; ++r)
        C[(size_t)(mbase + r) * N + n] = acc[i][j][r] + bv;
    }
  }
}

extern "C" void kernel_launch(void* const* d_in, const int* in_sizes, int n_in,
                              void* d_out, int out_size, void* d_ws, size_t ws_size,
                              hipStream_t stream) {
  const float* x = (const float*)d_in[0];
  const int* qw = (const int*)d_in[1];
  const float* sc = (const float*)d_in[2];
  const float* bias = (const float*)d_in[3];
  float* out = (float*)d_out;

  const long O = in_sizes[3];
  const long I = in_sizes[1] / O;        // 4096
  const long M = in_sizes[0] / I;        // 8192
  const long G = I / (in_sizes[2] / O);  // 128

  bf16_t* xb = (bf16_t*)d_ws;
  bf16_t* wb = xb + (size_t)M * I;
  const size_t need = ((size_t)M * I + (size_t)O * I) * sizeof(bf16_t);
  if (ws_size < need) return;

  cvt_x_kernel<<<2048, 256, 0, stream>>>(x, xb, M * I / 8);

  dim3 dgrid((unsigned)((I / 8 + 255) / 256), (unsigned)O);
  deq_w_kernel<<<dgrid, 256, 0, stream>>>(qw, sc, wb, (int)I, (int)G);

  if ((M & 255) == 0 && (O & 255) == 0 && (I & 127) == 0 && I >= 256) {
    const int nwg = (int)((M >> 8) * (O >> 8));
    gemm256_kernel<<<nwg, 512, 0, stream>>>(xb, wb, bias, out, (int)M, (int)O, (int)I);
  } else {
    dim3 ggrid((unsigned)(O / BM), (unsigned)(M / BM));
    gemm_bt_kernel<<<ggrid, 256, 0, stream>>>(xb, wb, bias, out, (int)M, (int)O, (int)I);
  }
}